// Round 5
// baseline (547.404 us; speedup 1.0000x reference)
//
#include <hip/hip_runtime.h>
#include <cstdint>

#define IN_DIM 256
#define OUT_DIM 27
#define NK1 9           // N_KNOTS + 1
#define WT_STRIDE 32    // padded row stride of transposed W (floats)

// ---------------------------------------------------------------------------
// Kernel 1: transpose W[27][256] -> Wt[k][nn] with padded stride 32, so the
// GEMV inner loop reads W with uniform (scalar) contiguous addresses.
// ---------------------------------------------------------------------------
__global__ void wt_transpose(const float* __restrict__ W, float* __restrict__ Wt) {
    int idx = blockIdx.x * 256 + threadIdx.x;
    if (idx < OUT_DIM * IN_DIM) {
        int nn = idx >> 8;    // / IN_DIM
        int k  = idx & 255;   // % IN_DIM
        Wt[k * WT_STRIDE + nn] = W[idx];
    }
}

__device__ __forceinline__ double softplus_d(double x) {
    // jax.nn.softplus = max(x,0) + log1p(exp(-|x|)), evaluated in f64
    return fmax(x, 0.0) + log1p(exp(-fabs(x)));
}

// ---------------------------------------------------------------------------
// Kernel 2: fused GEMV (fp32) + softplus/RQS/log-prob (f64 internals).
// 256 threads/block, 2 threads per row (split K in GEMV, split edges in eval).
// ROWS=128 rows per block. h staged via LDS [ROWS][CK+1] (conflict-free).
//
// Precision note: the harness compares against a float64 numpy reference with
// a threshold derived from JAX-fp32's own error (~0.311). probs can be ~1e-8
// while F is O(1), so fp32 F-subtraction loses ~7 digits. All post-GEMV math
// runs in double so the F(e)-F(e-1) cancellation is exact to ~1e-16; the
// remaining error is the fp32 GEMV logit error (~2e-6 -> ~1e-5 in log-probs).
// ---------------------------------------------------------------------------
template<bool USE_WT, int ROWS, int CK>
__global__ __launch_bounds__(256)
void rqs_head(const float* __restrict__ h, const float* __restrict__ Wmat,
              const float* __restrict__ b, float* __restrict__ out) {
    __shared__ float sh[ROWS][CK + 1];   // +1 pad: (row+k)%32 banks, 2-way max
    const int t    = threadIdx.x;
    const int rl   = t >> 1;             // local row 0..127
    const int half = t & 1;              // K-half / edge-half
    const long row0 = (long)blockIdx.x * ROWS;

    float acc[OUT_DIM];
    #pragma unroll
    for (int i = 0; i < OUT_DIM; ++i) acc[i] = 0.0f;

    constexpr int F4T = ROWS * CK / (4 * 256);  // float4 loads per thread per chunk
    constexpr int TPR = CK / 4;                 // threads per row during load
    constexpr int RPP = 256 / TPR;              // rows per load pass

    for (int kc = 0; kc < IN_DIM / CK; ++kc) {
        __syncthreads();
        #pragma unroll
        for (int p = 0; p < F4T; ++p) {
            const int r  = p * RPP + (t / TPR);
            const int fq = t % TPR;
            const float4 v = *reinterpret_cast<const float4*>(
                &h[(row0 + r) * IN_DIM + (size_t)kc * CK + fq * 4]);
            sh[r][fq * 4 + 0] = v.x;
            sh[r][fq * 4 + 1] = v.y;
            sh[r][fq * 4 + 2] = v.z;
            sh[r][fq * 4 + 3] = v.w;
        }
        __syncthreads();
        // each half-thread covers CK/2 k-values of this chunk
        #pragma unroll
        for (int kk = 0; kk < CK / 2; ++kk) {
            const int   kl = half * (CK / 2) + kk;
            const float hv = sh[rl][kl];
            const int   kg = kc * CK + kl;
            #pragma unroll
            for (int nn = 0; nn < OUT_DIM; ++nn) {
                const float wv = USE_WT ? Wmat[kg * WT_STRIDE + nn]
                                        : Wmat[nn * IN_DIM + kg];     // uniform -> s_load
                acc[nn] = fmaf(hv, wv, acc[nn]);
            }
        }
    }

    // combine the two K-halves (lane pairs t, t^1 share a row)
    #pragma unroll
    for (int nn = 0; nn < OUT_DIM; ++nn)
        acc[nn] += __shfl_xor(acc[nn], 1);

    // ---- params in f64: softplus(logits + b) + 1e-4 ----
    double pr[OUT_DIM];
    #pragma unroll
    for (int nn = 0; nn < OUT_DIM; ++nn)
        pr[nn] = softplus_d((double)acc[nn] + (double)b[nn]) + 1e-4;

    double wsum = 0.0, hsum = 0.0;
    #pragma unroll
    for (int i = 0; i < NK1; ++i) { wsum += pr[i]; hsum += pr[NK1 + i]; }
    const double iws = 1.0 / wsum, ihs = 1.0 / hsum;

    double cumx[NK1 + 1], cumy[NK1 + 1], wbn[NK1], hbn[NK1], dfull[NK1 + 1];
    cumx[0] = 0.0; cumy[0] = 0.0; dfull[0] = 1.0;
    #pragma unroll
    for (int i = 0; i < NK1; ++i) {
        wbn[i] = pr[i] * iws;
        hbn[i] = pr[NK1 + i] * ihs;
        cumx[i + 1]  = cumx[i] + wbn[i];
        cumy[i + 1]  = cumy[i] + hbn[i];
        dfull[i + 1] = pr[2 * NK1 + i];    // right-pad 1.0 is never read (bin<=8)
    }

    // ---- RQS eval: two-pointer walk, bins macro-unrolled (all reg indices
    // compile-time; runtime-indexed arrays would spill to scratch) ----
    const int e0   = half * 64;            // half 0: F(0..64) -> probs 0..63
    const int eend = e0 + 64;              // half 1: F(64..128) -> probs 64..127
    int e = e0;
    double prevF = 0.0;
    float* orow = out + (row0 + rl) * 128;

#define BIN_BODY(bin_) { \
        const double cx  = cumx[bin_]; \
        const double cxn = ((bin_) < 8) ? cumx[(bin_) + 1] : 1.0e300; \
        const double cy  = cumy[bin_]; \
        const double wb  = wbn[bin_]; \
        const double hb  = hbn[bin_]; \
        const double iw  = 1.0 / wb; \
        const double dl  = hb * iw; \
        const double db  = dfull[bin_]; \
        const double db1 = dfull[(bin_) + 1]; \
        const double sc  = db + db1 - 2.0 * dl; \
        while (e <= eend) { \
            const double x = (double)e * (1.0 / 128.0); \
            if (x > cxn) break;  /* searchsorted-left: first bin with cumx[bin+1] >= x */ \
            const double th  = (x - cx) * iw; \
            const double t1m = th * (1.0 - th); \
            const double num = hb * (dl * th * th + db * t1m); \
            const double den = dl + sc * t1m; \
            const double F   = cy + num / den; \
            if (e > e0) orow[e - 1] = logf(fmaxf((float)(F - prevF), 1e-8f)); \
            prevF = F; \
            ++e; \
        } }

    BIN_BODY(0) BIN_BODY(1) BIN_BODY(2) BIN_BODY(3) BIN_BODY(4)
    BIN_BODY(5) BIN_BODY(6) BIN_BODY(7) BIN_BODY(8)
#undef BIN_BODY
}

// ---------------------------------------------------------------------------
extern "C" void kernel_launch(void* const* d_in, const int* in_sizes, int n_in,
                              void* d_out, int out_size, void* d_ws, size_t ws_size,
                              hipStream_t stream) {
    const float* h = (const float*)d_in[0];
    const float* W = (const float*)d_in[1];
    const float* b = (const float*)d_in[2];
    float* out = (float*)d_out;

    const int rows = in_sizes[0] / IN_DIM;   // 131072
    constexpr int ROWS = 128, CK = 32;
    const int grid = rows / ROWS;            // 1024 blocks

    if (ws_size >= (size_t)(IN_DIM * WT_STRIDE * sizeof(float))) {
        float* Wt = (float*)d_ws;
        wt_transpose<<<OUT_DIM, 256, 0, stream>>>(W, Wt);
        rqs_head<true, ROWS, CK><<<grid, 256, 0, stream>>>(h, Wt, b, out);
    } else {
        rqs_head<false, ROWS, CK><<<grid, 256, 0, stream>>>(h, W, b, out);
    }
}

// Round 7
// 499.879 us; speedup vs baseline: 1.0951x; 1.0951x over previous
//
#include <hip/hip_runtime.h>
#include <cstdint>
#include <math.h>

#define IN_DIM 256
#define OUT_DIM 27
#define NK1 9            // N_KNOTS + 1
#define WT_STRIDE 32     // padded row stride of transposed W (floats), 128B
#define PSTRIDE 28       // padded param row stride (floats), 112B = 7 float4

// ---------------------------------------------------------------------------
// Kernel 1: transpose W[27][256] -> Wt[k][nn] (stride 32) so the GEMV reads W
// with wave-uniform contiguous addresses -> s_load_dwordx4/x8/x16.
// ---------------------------------------------------------------------------
__global__ void wt_transpose(const float* __restrict__ W, float* __restrict__ Wt) {
    int idx = blockIdx.x * 256 + threadIdx.x;
    if (idx < OUT_DIM * IN_DIM) {
        int nn = idx >> 8;
        int k  = idx & 255;
        Wt[k * WT_STRIDE + nn] = W[idx];
    }
}

// ---------------------------------------------------------------------------
// Kernel A: GEMV + fp32 softplus. Wave = 64 rows, one row per lane, full K.
// W access is wave-uniform (k loop counter only) -> scalar loads on the
// scalar pipe; h value comes from LDS [32][65] (bank = (k2+lane)%32, 2-way
// aliasing = free). Register double-buffer: chunk kc+1's global loads are
// issued before chunk kc's FMA phase (T14 async split).
// params[row][0..26] = softplus(logit)+1e-4 stored fp32 (err ~6e-8 rel,
// subdominant to the fp32 GEMV's ~1e-6 logit error).
// ---------------------------------------------------------------------------
__global__ __launch_bounds__(256, 2)
void gemv_params(const float* __restrict__ h, const float* __restrict__ Wt,
                 const float* __restrict__ bias, float* __restrict__ params)
{
    __shared__ float sh[4 * 32 * 65];          // 4 wave regions x [32][65] = 33.3 KB
    const int t    = threadIdx.x;
    const int w    = t >> 6;                   // wave 0..3
    const int lane = t & 63;
    const size_t row0 = (size_t)blockIdx.x * 256;

    float acc[OUT_DIM];
#pragma unroll
    for (int i = 0; i < OUT_DIM; ++i) acc[i] = 0.f;

    const int lr = t >> 3;   // staging row-sub 0..31
    const int lc = t & 7;    // staging float4 col 0..7

    float4 stg[2][8];

#define ISSUE_LOADS(kc_, buf_)                                                   \
    _Pragma("unroll")                                                            \
    for (int p = 0; p < 8; ++p) {                                                \
        const size_t rr = row0 + (size_t)(p * 32 + lr);                          \
        stg[buf_][p] = *reinterpret_cast<const float4*>(                         \
            h + rr * IN_DIM + (kc_) * 32 + lc * 4);                              \
    }

#define WRITE_LDS(buf_)                                                          \
    _Pragma("unroll")                                                            \
    for (int p = 0; p < 8; ++p) {                                                \
        const int r  = p * 32 + lr;                                              \
        float* base  = &sh[(r >> 6) * 2080];                                     \
        const int rl = r & 63;                                                   \
        base[(lc * 4 + 0) * 65 + rl] = stg[buf_][p].x;                           \
        base[(lc * 4 + 1) * 65 + rl] = stg[buf_][p].y;                           \
        base[(lc * 4 + 2) * 65 + rl] = stg[buf_][p].z;                           \
        base[(lc * 4 + 3) * 65 + rl] = stg[buf_][p].w;                           \
    }

    ISSUE_LOADS(0, 0);
#pragma unroll
    for (int kc = 0; kc < 8; ++kc) {
        __syncthreads();                       // previous chunk's reads complete
        if (kc & 1) { WRITE_LDS(1); } else { WRITE_LDS(0); }
        if (kc < 7) {
            if (kc & 1) { ISSUE_LOADS(kc + 1, 0); } else { ISSUE_LOADS(kc + 1, 1); }
        }
        __syncthreads();                       // LDS chunk visible
        const float* myld = &sh[w * 2080];
#pragma unroll
        for (int k2 = 0; k2 < 32; ++k2) {
            const float hv = myld[k2 * 65 + lane];
            const float* wrow = (const float*)__builtin_assume_aligned(
                Wt + (size_t)(kc * 32 + k2) * WT_STRIDE, 128);  // wave-uniform -> s_load
#pragma unroll
            for (int nn = 0; nn < OUT_DIM; ++nn)
                acc[nn] = fmaf(hv, wrow[nn], acc[nn]);
        }
    }
#undef ISSUE_LOADS
#undef WRITE_LDS

    // epilogue: bias + softplus (fp32) + 1e-4, padded float4 store
    const size_t row = row0 + (size_t)w * 64 + lane;
    float pv[PSTRIDE];
#pragma unroll
    for (int nn = 0; nn < OUT_DIM; ++nn) {
        const float x = acc[nn] + bias[nn];
        pv[nn] = fmaxf(x, 0.f) + log1pf(expf(-fabsf(x))) + 1e-4f;
    }
    pv[27] = 0.f;
    float4* pp = reinterpret_cast<float4*>(params + row * PSTRIDE);
#pragma unroll
    for (int i = 0; i < 7; ++i)
        pp[i] = make_float4(pv[4*i], pv[4*i+1], pv[4*i+2], pv[4*i+3]);
}

// ---------------------------------------------------------------------------
// fast f64 reciprocal: v_rcp_f32 seed (~1e-7 rel) + 2 f64 Newton -> ~1-2 ulp.
// Replaces the ~25-inst library f64 divide with ~8 ops.
// ---------------------------------------------------------------------------
__device__ __forceinline__ double fast_rcp(double d) {
    double r = (double)__builtin_amdgcn_rcpf((float)d);
    r = r * (2.0 - d * r);
    r = r * (2.0 - d * r);
    return r;
}

// ---------------------------------------------------------------------------
// Kernel B: RQS spline + log-prob. 4 threads/row (8192 waves -> latency-
// hiding). f64 only where cancellation lives: cumsum, F, F-prevF. No library
// f64 divides (fast_rcp). Final log via __logf (err ~3e-6 abs, unamplified).
// ---------------------------------------------------------------------------
__global__ __launch_bounds__(256)
void spline_eval(const float* __restrict__ params, float* __restrict__ out, int nrows)
{
    const int t   = blockIdx.x * 256 + threadIdx.x;
    const int row = t >> 2;
    const int q   = t & 3;
    if (row >= nrows) return;

    const float4* pp = reinterpret_cast<const float4*>(params + (size_t)row * PSTRIDE);
    float pr[PSTRIDE];
#pragma unroll
    for (int i = 0; i < 7; ++i) {
        const float4 v = pp[i];
        pr[4*i] = v.x; pr[4*i+1] = v.y; pr[4*i+2] = v.z; pr[4*i+3] = v.w;
    }

    double wsum = 0.0, hsum = 0.0;
#pragma unroll
    for (int i = 0; i < NK1; ++i) { wsum += (double)pr[i]; hsum += (double)pr[NK1 + i]; }
    const double iws = fast_rcp(wsum), ihs = fast_rcp(hsum);

    double cumx[NK1 + 1], cumy[NK1 + 1], dfull[NK1 + 1];
    cumx[0] = 0.0; cumy[0] = 0.0; dfull[0] = 1.0;
#pragma unroll
    for (int i = 0; i < NK1; ++i) {
        cumx[i + 1]  = cumx[i] + (double)pr[i] * iws;
        cumy[i + 1]  = cumy[i] + (double)pr[NK1 + i] * ihs;
        dfull[i + 1] = (double)pr[2 * NK1 + i];   // right-pad 1.0 never read
    }

    const int e0 = q * 32, eend = e0 + 32;        // F(e0..e0+32) -> probs e0..e0+31
    int e = e0;
    double prevF = 0.0;
    float* orow = out + (size_t)row * 128;

#define BIN_BODY(bin_) { \
    const double cx  = cumx[bin_]; \
    const double cxn = ((bin_) < 8) ? cumx[(bin_) + 1] : 1.0e300; \
    const double cy  = cumy[bin_]; \
    const double wb  = cumx[(bin_) + 1] - cx; \
    const double hb  = cumy[(bin_) + 1] - cy; \
    const double iw  = fast_rcp(wb); \
    const double dl  = hb * iw; \
    const double db  = dfull[bin_]; \
    const double db1 = dfull[(bin_) + 1]; \
    const double sc  = db + db1 - 2.0 * dl; \
    while (e <= eend) { \
        const double x = (double)e * 0.0078125; \
        if (x > cxn) break;  /* searchsorted-left: first bin with cumx[bin+1] >= x */ \
        const double th  = (x - cx) * iw; \
        const double t1m = th * (1.0 - th); \
        const double num = hb * (dl * th * th + db * t1m); \
        const double den = dl + sc * t1m; \
        const double F   = cy + num * fast_rcp(den); \
        if (e > e0) orow[e - 1] = __logf(fmaxf((float)(F - prevF), 1e-8f)); \
        prevF = F; \
        ++e; \
    } }

    BIN_BODY(0) BIN_BODY(1) BIN_BODY(2) BIN_BODY(3) BIN_BODY(4)
    BIN_BODY(5) BIN_BODY(6) BIN_BODY(7) BIN_BODY(8)
#undef BIN_BODY
}

// ---------------------------------------------------------------------------
// Fallback (ws too small): R5's proven monolithic kernel, per-lane W loads.
// ---------------------------------------------------------------------------
__device__ __forceinline__ double softplus_d(double x) {
    return fmax(x, 0.0) + log1p(exp(-fabs(x)));
}

__global__ __launch_bounds__(256)
void rqs_head_fallback(const float* __restrict__ h, const float* __restrict__ Wmat,
                       const float* __restrict__ b, float* __restrict__ out) {
    __shared__ float sh[128][33];
    const int t = threadIdx.x, rl = t >> 1, half = t & 1;
    const long row0 = (long)blockIdx.x * 128;
    float acc[OUT_DIM];
#pragma unroll
    for (int i = 0; i < OUT_DIM; ++i) acc[i] = 0.0f;
    for (int kc = 0; kc < 8; ++kc) {
        __syncthreads();
#pragma unroll
        for (int p = 0; p < 4; ++p) {
            const int r = p * 32 + (t / 8), fq = t % 8;
            const float4 v = *reinterpret_cast<const float4*>(
                &h[(row0 + r) * IN_DIM + (size_t)kc * 32 + fq * 4]);
            sh[r][fq*4+0]=v.x; sh[r][fq*4+1]=v.y; sh[r][fq*4+2]=v.z; sh[r][fq*4+3]=v.w;
        }
        __syncthreads();
#pragma unroll
        for (int kk = 0; kk < 16; ++kk) {
            const int kl = half * 16 + kk;
            const float hv = sh[rl][kl];
            const int kg = kc * 32 + kl;
#pragma unroll
            for (int nn = 0; nn < OUT_DIM; ++nn)
                acc[nn] = fmaf(hv, Wmat[nn * IN_DIM + kg], acc[nn]);
        }
    }
#pragma unroll
    for (int nn = 0; nn < OUT_DIM; ++nn) acc[nn] += __shfl_xor(acc[nn], 1);
    double pr[OUT_DIM];
#pragma unroll
    for (int nn = 0; nn < OUT_DIM; ++nn)
        pr[nn] = softplus_d((double)acc[nn] + (double)b[nn]) + 1e-4;
    double wsum = 0.0, hsum = 0.0;
#pragma unroll
    for (int i = 0; i < NK1; ++i) { wsum += pr[i]; hsum += pr[NK1 + i]; }
    const double iws = 1.0 / wsum, ihs = 1.0 / hsum;
    double cumx[NK1+1], cumy[NK1+1], dfull[NK1+1];
    cumx[0]=0.0; cumy[0]=0.0; dfull[0]=1.0;
#pragma unroll
    for (int i = 0; i < NK1; ++i) {
        cumx[i+1] = cumx[i] + pr[i]*iws;
        cumy[i+1] = cumy[i] + pr[NK1+i]*ihs;
        dfull[i+1] = pr[2*NK1+i];
    }
    const int e0 = half * 64, eend = e0 + 64;
    int e = e0; double prevF = 0.0;
    float* orow = out + (row0 + rl) * 128;
#define BIN_BODY(bin_) { \
    const double cx=cumx[bin_], cxn=((bin_)<8)?cumx[(bin_)+1]:1.0e300, cy=cumy[bin_]; \
    const double wb=cumx[(bin_)+1]-cx, hb=cumy[(bin_)+1]-cy; \
    const double iw=1.0/wb, dl=hb*iw, db=dfull[bin_], db1=dfull[(bin_)+1]; \
    const double sc=db+db1-2.0*dl; \
    while (e <= eend) { \
        const double x=(double)e*0.0078125; \
        if (x > cxn) break; \
        const double th=(x-cx)*iw, t1m=th*(1.0-th); \
        const double num=hb*(dl*th*th+db*t1m), den=dl+sc*t1m; \
        const double F=cy+num/den; \
        if (e > e0) orow[e-1] = logf(fmaxf((float)(F-prevF), 1e-8f)); \
        prevF=F; ++e; \
    } }
    BIN_BODY(0) BIN_BODY(1) BIN_BODY(2) BIN_BODY(3) BIN_BODY(4)
    BIN_BODY(5) BIN_BODY(6) BIN_BODY(7) BIN_BODY(8)
#undef BIN_BODY
}

// ---------------------------------------------------------------------------
extern "C" void kernel_launch(void* const* d_in, const int* in_sizes, int n_in,
                              void* d_out, int out_size, void* d_ws, size_t ws_size,
                              hipStream_t stream) {
    const float* h = (const float*)d_in[0];
    const float* W = (const float*)d_in[1];
    const float* b = (const float*)d_in[2];
    float* out = (float*)d_out;

    const int rows = in_sizes[0] / IN_DIM;   // 131072
    const size_t wt_bytes = (size_t)IN_DIM * WT_STRIDE * sizeof(float);   // 32 KB
    const size_t pr_bytes = (size_t)rows * PSTRIDE * sizeof(float);       // 14.7 MB

    if (ws_size >= wt_bytes + pr_bytes) {
        float* Wt     = (float*)d_ws;
        float* params = (float*)d_ws + IN_DIM * WT_STRIDE;
        wt_transpose<<<OUT_DIM, 256, 0, stream>>>(W, Wt);
        gemv_params <<<rows / 256,      256, 0, stream>>>(h, Wt, b, params);
        spline_eval <<<rows * 4 / 256,  256, 0, stream>>>(params, out, rows);
    } else {
        rqs_head_fallback<<<rows / 128, 256, 0, stream>>>(h, W, b, out);
    }
}

// Round 8
// 385.703 us; speedup vs baseline: 1.4192x; 1.2960x over previous
//
#include <hip/hip_runtime.h>
#include <cstdint>
#include <math.h>

#define IN_DIM 256
#define OUT_DIM 27
#define NK1 9            // N_KNOTS + 1
#define WT_STRIDE 32     // padded row stride of transposed W (floats), 128B

// ---------------------------------------------------------------------------
// Kernel 1: transpose W[27][256] -> Wt[k][nn] (stride 32): GEMV reads W with
// wave-uniform addresses -> scalar (s_load) path.
// ---------------------------------------------------------------------------
__global__ void wt_transpose(const float* __restrict__ W, float* __restrict__ Wt) {
    int idx = blockIdx.x * 256 + threadIdx.x;
    if (idx < OUT_DIM * IN_DIM) {
        int nn = idx >> 8;
        int k  = idx & 255;
        Wt[k * WT_STRIDE + nn] = W[idx];
    }
}

// ---------------------------------------------------------------------------
// Kernel A v2: GEMV + fp32 softplus -> paramsT[27][nrows] (planar, coalesced).
// 64 rows/block, 4 waves k-split (wave w: k in [64w, 64w+64)). Each wave
// stages h chunks into a PRIVATE LDS region [16][66] with NO barriers in the
// K-loop (intra-wave LDS ordering is in-order; regions are disjoint). One
// barrier pair at the end for the cross-wave reduce (LDS reused).
// ---------------------------------------------------------------------------
__global__ __launch_bounds__(256)
void gemv_params2(const float* __restrict__ h, const float* __restrict__ Wt,
                  const float* __restrict__ bias, float* __restrict__ paramsT,
                  int nrows)
{
    __shared__ float red[4 * 64 * 29];        // 29.7 KB; front 4224 floats = staging
    const int t = threadIdx.x;
    const int w = t >> 6;                     // wave 0..3 (k-quarter)
    const int l = t & 63;                     // lane = local row
    const size_t row0 = (size_t)blockIdx.x * 64;

    float acc[OUT_DIM];
#pragma unroll
    for (int i = 0; i < OUT_DIM; ++i) acc[i] = 0.f;

    float* shg = &red[w * 1056];              // private [16][66] staging
    const int pr_ = l >> 2;                   // row-sub 0..15 during load
    const int pc_ = l & 3;                    // float4 col 0..3

#pragma unroll
    for (int c = 0; c < 4; ++c) {             // 4 chunks of 16 k
        float4 v[4];
#pragma unroll
        for (int p = 0; p < 4; ++p) {
            const size_t row = row0 + p * 16 + pr_;
            v[p] = *reinterpret_cast<const float4*>(
                h + row * IN_DIM + w * 64 + c * 16 + pc_ * 4);
        }
#pragma unroll
        for (int p = 0; p < 4; ++p) {
            const int row = p * 16 + pr_;
            shg[(pc_ * 4 + 0) * 66 + row] = v[p].x;
            shg[(pc_ * 4 + 1) * 66 + row] = v[p].y;
            shg[(pc_ * 4 + 2) * 66 + row] = v[p].z;
            shg[(pc_ * 4 + 3) * 66 + row] = v[p].w;
        }
#pragma unroll
        for (int k2 = 0; k2 < 16; ++k2) {
            const float hv = shg[k2 * 66 + l];                 // lane owns row l
            const float* wrow = Wt + (size_t)(w * 64 + c * 16 + k2) * WT_STRIDE;
#pragma unroll
            for (int nn = 0; nn < OUT_DIM; ++nn)
                acc[nn] = fmaf(hv, wrow[nn], acc[nn]);         // wrow uniform -> s_load
        }
    }

    __syncthreads();                          // staging dead -> reuse as reduce buf
#pragma unroll
    for (int nn = 0; nn < OUT_DIM; ++nn)
        red[(w * 64 + l) * 29 + nn] = acc[nn];
    __syncthreads();

    const int row = t & 63;
    const int grp = t >> 6;
    const int nn0 = grp * 7;
    const int nn1 = (nn0 + 7 < OUT_DIM) ? nn0 + 7 : OUT_DIM;
    for (int nn = nn0; nn < nn1; ++nn) {
        const float s = red[(0 * 64 + row) * 29 + nn] + red[(1 * 64 + row) * 29 + nn]
                      + red[(2 * 64 + row) * 29 + nn] + red[(3 * 64 + row) * 29 + nn];
        const float x  = s + bias[nn];
        const float sp = fmaxf(x, 0.f) + log1pf(expf(-fabsf(x))) + 1e-4f;
        paramsT[(size_t)nn * nrows + row0 + row] = sp;         // planar, coalesced
    }
}

// ---------------------------------------------------------------------------
// fast f64 reciprocal: v_rcp_f32 seed + 2 f64 Newton -> ~1-2 ulp f64.
// ---------------------------------------------------------------------------
__device__ __forceinline__ double fast_rcp(double d) {
    double r = (double)__builtin_amdgcn_rcpf((float)d);
    r = r * (2.0 - d * r);
    r = r * (2.0 - d * r);
    return r;
}

// ---------------------------------------------------------------------------
// Kernel B v2: one thread per edge. Block = 256 threads = 2 rows x 128 edges.
// Per row: coeffs (cumx/cumy/d in f64) built once into LDS; every thread does
// ONE branchless f64 spline eval; prob[e] = F(e+1)-F(e) via shfl_down (seam
// lane e%64==63 re-evals; e==127 uses cumy[9]). Coalesced 4B stores.
// f64 kept for the whole eval chain (the F-subtraction cancellation).
// ---------------------------------------------------------------------------
__global__ __launch_bounds__(256)
void spline_eval2(const float* __restrict__ paramsT, float* __restrict__ out,
                  int nrows)
{
    __shared__ double scx[2][10], scy[2][10], sdd[2][10];
    const int t   = threadIdx.x;
    const int sub = t >> 7;                   // row half 0/1
    const int e   = t & 127;                  // edge 0..127
    const size_t rowg = (size_t)blockIdx.x * 2 + sub;

    if (e == 0) {                             // per-row setup (1 thread/row)
        double pr[OUT_DIM];
#pragma unroll
        for (int j = 0; j < OUT_DIM; ++j)
            pr[j] = (double)paramsT[(size_t)j * nrows + rowg];
        double ws = 0.0, hs = 0.0;
#pragma unroll
        for (int i = 0; i < NK1; ++i) { ws += pr[i]; hs += pr[NK1 + i]; }
        const double iws = fast_rcp(ws), ihs = fast_rcp(hs);
        double cx = 0.0, cy = 0.0;
        scx[sub][0] = 0.0; scy[sub][0] = 0.0; sdd[sub][0] = 1.0;
#pragma unroll
        for (int i = 0; i < NK1; ++i) {
            cx += pr[i] * iws;
            cy += pr[NK1 + i] * ihs;
            scx[sub][i + 1] = cx;
            scy[sub][i + 1] = cy;
            sdd[sub][i + 1] = pr[2 * NK1 + i];   // d_full[1..9]; d_full[10] never read
        }
    }
    __syncthreads();

    const double* cxr = scx[sub];
    const double* cyr = scy[sub];
    const double* ddr = sdd[sub];

    auto evalF = [&](double x) -> double {
        // searchsorted-left on cumx[1..9]: b = #{cumx[i] < x}, clamped to 8
        int b = 0;
#pragma unroll
        for (int i = 1; i <= 9; ++i) b += (cxr[i] < x) ? 1 : 0;
        b = (b < 8) ? b : 8;
        const double cxb = cxr[b], cxb1 = cxr[b + 1];
        const double cyb = cyr[b], cyb1 = cyr[b + 1];
        const double db  = ddr[b], db1  = ddr[b + 1];
        const double wb  = cxb1 - cxb;
        const double hb  = cyb1 - cyb;
        const double iw  = fast_rcp(wb);
        const double dl  = hb * iw;
        const double th  = (x - cxb) * iw;
        const double t1m = th * (1.0 - th);
        const double num = hb * (dl * th * th + db * t1m);
        const double den = dl + (db + db1 - 2.0 * dl) * t1m;
        return cyb + num * fast_rcp(den);
    };

    const double F0 = evalF((double)e * 0.0078125);
    double F1 = __shfl_down(F0, 1);
    if ((e & 63) == 63) {
        F1 = (e == 127) ? cyr[9] : evalF((double)(e + 1) * 0.0078125);
    }
    out[rowg * 128 + e] = __logf(fmaxf((float)(F1 - F0), 1e-8f));
}

// ---------------------------------------------------------------------------
// Fallback (ws too small): R5/R7's proven monolithic kernel.
// ---------------------------------------------------------------------------
__device__ __forceinline__ double softplus_d(double x) {
    return fmax(x, 0.0) + log1p(exp(-fabs(x)));
}

__global__ __launch_bounds__(256)
void rqs_head_fallback(const float* __restrict__ h, const float* __restrict__ Wmat,
                       const float* __restrict__ b, float* __restrict__ out) {
    __shared__ float sh[128][33];
    const int t = threadIdx.x, rl = t >> 1, half = t & 1;
    const long row0 = (long)blockIdx.x * 128;
    float acc[OUT_DIM];
#pragma unroll
    for (int i = 0; i < OUT_DIM; ++i) acc[i] = 0.0f;
    for (int kc = 0; kc < 8; ++kc) {
        __syncthreads();
#pragma unroll
        for (int p = 0; p < 4; ++p) {
            const int r = p * 32 + (t / 8), fq = t % 8;
            const float4 v = *reinterpret_cast<const float4*>(
                &h[(row0 + r) * IN_DIM + (size_t)kc * 32 + fq * 4]);
            sh[r][fq*4+0]=v.x; sh[r][fq*4+1]=v.y; sh[r][fq*4+2]=v.z; sh[r][fq*4+3]=v.w;
        }
        __syncthreads();
#pragma unroll
        for (int kk = 0; kk < 16; ++kk) {
            const int kl = half * 16 + kk;
            const float hv = sh[rl][kl];
            const int kg = kc * 32 + kl;
#pragma unroll
            for (int nn = 0; nn < OUT_DIM; ++nn)
                acc[nn] = fmaf(hv, Wmat[nn * IN_DIM + kg], acc[nn]);
        }
    }
#pragma unroll
    for (int nn = 0; nn < OUT_DIM; ++nn) acc[nn] += __shfl_xor(acc[nn], 1);
    double pr[OUT_DIM];
#pragma unroll
    for (int nn = 0; nn < OUT_DIM; ++nn)
        pr[nn] = softplus_d((double)acc[nn] + (double)b[nn]) + 1e-4;
    double wsum = 0.0, hsum = 0.0;
#pragma unroll
    for (int i = 0; i < NK1; ++i) { wsum += pr[i]; hsum += pr[NK1 + i]; }
    const double iws = 1.0 / wsum, ihs = 1.0 / hsum;
    double cumx[NK1+1], cumy[NK1+1], dfull[NK1+1];
    cumx[0]=0.0; cumy[0]=0.0; dfull[0]=1.0;
#pragma unroll
    for (int i = 0; i < NK1; ++i) {
        cumx[i+1] = cumx[i] + pr[i]*iws;
        cumy[i+1] = cumy[i] + pr[NK1+i]*ihs;
        dfull[i+1] = pr[2*NK1+i];
    }
    const int e0 = half * 64, eend = e0 + 64;
    int e = e0; double prevF = 0.0;
    float* orow = out + (row0 + rl) * 128;
#define BIN_BODY(bin_) { \
    const double cx=cumx[bin_], cxn=((bin_)<8)?cumx[(bin_)+1]:1.0e300, cy=cumy[bin_]; \
    const double wb=cumx[(bin_)+1]-cx, hb=cumy[(bin_)+1]-cy; \
    const double iw=1.0/wb, dl=hb*iw, db=dfull[bin_], db1=dfull[(bin_)+1]; \
    const double sc=db+db1-2.0*dl; \
    while (e <= eend) { \
        const double x=(double)e*0.0078125; \
        if (x > cxn) break; \
        const double th=(x-cx)*iw, t1m=th*(1.0-th); \
        const double num=hb*(dl*th*th+db*t1m), den=dl+sc*t1m; \
        const double F=cy+num/den; \
        if (e > e0) orow[e-1] = logf(fmaxf((float)(F-prevF), 1e-8f)); \
        prevF=F; ++e; \
    } }
    BIN_BODY(0) BIN_BODY(1) BIN_BODY(2) BIN_BODY(3) BIN_BODY(4)
    BIN_BODY(5) BIN_BODY(6) BIN_BODY(7) BIN_BODY(8)
#undef BIN_BODY
}

// ---------------------------------------------------------------------------
extern "C" void kernel_launch(void* const* d_in, const int* in_sizes, int n_in,
                              void* d_out, int out_size, void* d_ws, size_t ws_size,
                              hipStream_t stream) {
    const float* h = (const float*)d_in[0];
    const float* W = (const float*)d_in[1];
    const float* b = (const float*)d_in[2];
    float* out = (float*)d_out;

    const int rows = in_sizes[0] / IN_DIM;   // 131072
    const size_t wt_floats = (size_t)IN_DIM * WT_STRIDE;                  // 8192
    const size_t need = (wt_floats + (size_t)OUT_DIM * rows) * sizeof(float); // ~14.2 MB

    if (ws_size >= need) {
        float* Wt      = (float*)d_ws;
        float* paramsT = (float*)d_ws + wt_floats;
        wt_transpose <<<OUT_DIM,      256, 0, stream>>>(W, Wt);
        gemv_params2 <<<rows / 64,    256, 0, stream>>>(h, Wt, b, paramsT, rows);
        spline_eval2 <<<rows / 2,     256, 0, stream>>>(paramsT, out, rows);
    } else {
        rqs_head_fallback<<<rows / 128, 256, 0, stream>>>(h, W, b, out);
    }
}

// Round 9
// 301.119 us; speedup vs baseline: 1.8179x; 1.2809x over previous
//
#include <hip/hip_runtime.h>
#include <cstdint>
#include <math.h>

#define IN_DIM 256
#define OUT_DIM 27
#define NK1 9

// fast f64 reciprocal: v_rcp_f32 seed + 2 f64 Newton -> ~1-2 ulp f64,
// ~8 ops instead of the ~25-inst library f64 divide.
__device__ __forceinline__ double fast_rcp(double d) {
    double r = (double)__builtin_amdgcn_rcpf((float)d);
    r = r * (2.0 - d * r);
    r = r * (2.0 - d * r);
    return r;
}

// ---------------------------------------------------------------------------
// GEMV v3: 64 rows/block, 4 waves k-split (wave w: k in [64w,64w+64)).
// W[27][256] staged ONCE into LDS [k][28]; inner loop reads it as
// wave-uniform broadcast ds_read_b128 (conflict-free, vector pipe — no
// scalar-path lgkmcnt serialization, the R8 killer). h goes straight to
// 16 float4 VGPRs per lane (lane = row): 16 independent loads in flight,
// no barriers in the K-loop. Epilogue: cross-wave LDS reduce (reusing the
// W region), fp32 softplus, planar coalesced param store.
// ---------------------------------------------------------------------------
__global__ __launch_bounds__(256, 4)
void gemv_params3(const float* __restrict__ h, const float* __restrict__ W,
                  const float* __restrict__ bias, float* __restrict__ paramsT,
                  int nrows)
{
    __shared__ float wlds[IN_DIM * 28];        // [k][28], 28.7 KB (28th = pad)
    const int t = threadIdx.x;
    const int w = t >> 6, l = t & 63;
    const size_t row0 = (size_t)blockIdx.x * 64;

    // stage W transposed: thread t owns k = t (coalesced reads)
#pragma unroll
    for (int nn = 0; nn < OUT_DIM; ++nn)
        wlds[t * 28 + nn] = W[nn * IN_DIM + t];
    wlds[t * 28 + 27] = 0.f;
    __syncthreads();

    // h direct to regs AFTER the barrier: consumption overlaps the loads
    float4 hreg[16];
    const float* hbase = h + (row0 + l) * IN_DIM + w * 64;
#pragma unroll
    for (int j = 0; j < 16; ++j)
        hreg[j] = *reinterpret_cast<const float4*>(hbase + j * 4);

    float acc[28];
#pragma unroll
    for (int i = 0; i < 28; ++i) acc[i] = 0.f;

#pragma unroll
    for (int j = 0; j < 16; ++j) {
        const float4 hv4 = hreg[j];
#pragma unroll
        for (int kk = 0; kk < 4; ++kk) {
            const float hv = (kk == 0) ? hv4.x : (kk == 1) ? hv4.y
                           : (kk == 2) ? hv4.z : hv4.w;
            const float* wr = &wlds[(w * 64 + j * 4 + kk) * 28];
#pragma unroll
            for (int q = 0; q < 7; ++q) {
                const float4 wq = *reinterpret_cast<const float4*>(wr + q * 4);
                acc[q * 4 + 0] = fmaf(hv, wq.x, acc[q * 4 + 0]);
                acc[q * 4 + 1] = fmaf(hv, wq.y, acc[q * 4 + 1]);
                acc[q * 4 + 2] = fmaf(hv, wq.z, acc[q * 4 + 2]);
                acc[q * 4 + 3] = fmaf(hv, wq.w, acc[q * 4 + 3]);
            }
        }
    }

    __syncthreads();                           // done reading W; reuse as reduce buf
#pragma unroll
    for (int nn = 0; nn < OUT_DIM; ++nn)
        wlds[t * 28 + nn] = acc[nn];
    __syncthreads();

    const int row = t & 63, grp = t >> 6;
    const int nn0 = grp * 7;
    const int nnE = (nn0 + 7 < OUT_DIM) ? nn0 + 7 : OUT_DIM;
    for (int nn = nn0; nn < nnE; ++nn) {
        const float s = wlds[(0 * 64 + row) * 28 + nn] + wlds[(1 * 64 + row) * 28 + nn]
                      + wlds[(2 * 64 + row) * 28 + nn] + wlds[(3 * 64 + row) * 28 + nn];
        const float x  = s + bias[nn];
        const float sp = fmaxf(x, 0.f) + log1pf(expf(-fabsf(x))) + 1e-4f;
        paramsT[(size_t)nn * nrows + row0 + row] = sp;   // planar, coalesced
    }
}

// ---------------------------------------------------------------------------
// Spline v3: 4 rows/block x 64 lanes/row (row == one wave -> shfl seam ok),
// 2 edges per lane. Setup parallelized: 108 threads load params, 4 threads
// do the f64 scan + per-bin coeff table {cx, cy, iw, dl, hb, d, sc} (kills
// the per-eval rcp(wb)). Eval: 9 reg-resident f64 compares (searchsorted-
// left) + runtime-indexed LDS gather (stride 9 f64 -> distinct banks) +
// ~13 f64 ops + 1 fast_rcp. f64 everywhere the F-cancellation lives.
// ---------------------------------------------------------------------------
__global__ __launch_bounds__(256)
void spline_eval3(const float* __restrict__ paramsT, float* __restrict__ out,
                  int nrows)
{
    __shared__ float  sp[4][27];
    __shared__ double cxs[4][10];
    __shared__ double cf[4][9][9];     // [row][bin][{cx,cy,iw,dl,hb,db,sc,-,-}]
    const int t = threadIdx.x;
    const size_t r0 = (size_t)blockIdx.x * 4;

    if (t < 108) {
        const int j = t >> 2, r = t & 3;
        sp[r][j] = paramsT[(size_t)j * nrows + r0 + r];
    }
    __syncthreads();
    if (t < 4) {
        const int r = t;
        double ws = 0.0, hs = 0.0;
#pragma unroll
        for (int i = 0; i < NK1; ++i) { ws += (double)sp[r][i]; hs += (double)sp[r][NK1 + i]; }
        const double iws = fast_rcp(ws), ihs = fast_rcp(hs);
        double cumx[10], cumy[10];
        cumx[0] = 0.0; cumy[0] = 0.0;
#pragma unroll
        for (int i = 0; i < NK1; ++i) {
            cumx[i + 1] = cumx[i] + (double)sp[r][i] * iws;
            cumy[i + 1] = cumy[i] + (double)sp[r][NK1 + i] * ihs;
        }
#pragma unroll
        for (int b = 0; b < 9; ++b) {
            const double db  = (b == 0) ? 1.0 : (double)sp[r][2 * NK1 + b - 1];
            const double db1 = (double)sp[r][2 * NK1 + b];       // dfull[b+1], b<=8
            const double wb  = cumx[b + 1] - cumx[b];
            const double hb  = cumy[b + 1] - cumy[b];
            const double iw  = fast_rcp(wb);
            const double dl  = hb * iw;
            cf[r][b][0] = cumx[b];
            cf[r][b][1] = cumy[b];
            cf[r][b][2] = iw;
            cf[r][b][3] = dl;
            cf[r][b][4] = hb;
            cf[r][b][5] = db;
            cf[r][b][6] = db + db1 - 2.0 * dl;
            cxs[r][b]   = cumx[b];
        }
        cxs[r][9] = cumx[9];
    }
    __syncthreads();

    const int r  = t >> 6;             // row 0..3 (one wave per row)
    const int lq = t & 63;             // lane in row

    double cx_[9];                      // cumx[1..9] in regs for the compares
#pragma unroll
    for (int i = 0; i < 9; ++i) cx_[i] = cxs[r][i + 1];

    auto evalF = [&](double x) -> double {
        int b = 0;
#pragma unroll
        for (int i = 0; i < 9; ++i) b += (cx_[i] < x) ? 1 : 0;   // searchsorted-left
        b = (b < 8) ? b : 8;
        const double* c = cf[r][b];                               // LDS gather
        const double th  = (x - c[0]) * c[2];
        const double t1m = th * (1.0 - th);
        const double num = c[4] * (c[3] * th * th + c[5] * t1m);
        const double den = c[3] + c[6] * t1m;
        return c[1] + num * fast_rcp(den);
    };

    const double x0 = (double)(lq * 2) * 0.0078125;
    const double F0 = evalF(x0);
    const double F1 = evalF(x0 + 0.0078125);
    double F2 = __shfl_down(F0, 1);          // lane k+1's F(2k+2), bit-identical
    if (lq == 63) F2 = evalF(1.0);           // F(128)
    const float p0 = __logf(fmaxf((float)(F1 - F0), 1e-8f));
    const float p1 = __logf(fmaxf((float)(F2 - F1), 1e-8f));
    *reinterpret_cast<float2*>(out + (r0 + r) * 128 + lq * 2) = make_float2(p0, p1);
}

// ---------------------------------------------------------------------------
// Fallback (ws too small): R5/R8's proven monolithic kernel.
// ---------------------------------------------------------------------------
__device__ __forceinline__ double softplus_d(double x) {
    return fmax(x, 0.0) + log1p(exp(-fabs(x)));
}

__global__ __launch_bounds__(256)
void rqs_head_fallback(const float* __restrict__ h, const float* __restrict__ Wmat,
                       const float* __restrict__ b, float* __restrict__ out) {
    __shared__ float sh[128][33];
    const int t = threadIdx.x, rl = t >> 1, half = t & 1;
    const long row0 = (long)blockIdx.x * 128;
    float acc[OUT_DIM];
#pragma unroll
    for (int i = 0; i < OUT_DIM; ++i) acc[i] = 0.0f;
    for (int kc = 0; kc < 8; ++kc) {
        __syncthreads();
#pragma unroll
        for (int p = 0; p < 4; ++p) {
            const int r = p * 32 + (t / 8), fq = t % 8;
            const float4 v = *reinterpret_cast<const float4*>(
                &h[(row0 + r) * IN_DIM + (size_t)kc * 32 + fq * 4]);
            sh[r][fq*4+0]=v.x; sh[r][fq*4+1]=v.y; sh[r][fq*4+2]=v.z; sh[r][fq*4+3]=v.w;
        }
        __syncthreads();
#pragma unroll
        for (int kk = 0; kk < 16; ++kk) {
            const int kl = half * 16 + kk;
            const float hv = sh[rl][kl];
            const int kg = kc * 32 + kl;
#pragma unroll
            for (int nn = 0; nn < OUT_DIM; ++nn)
                acc[nn] = fmaf(hv, Wmat[nn * IN_DIM + kg], acc[nn]);
        }
    }
#pragma unroll
    for (int nn = 0; nn < OUT_DIM; ++nn) acc[nn] += __shfl_xor(acc[nn], 1);
    double pr[OUT_DIM];
#pragma unroll
    for (int nn = 0; nn < OUT_DIM; ++nn)
        pr[nn] = softplus_d((double)acc[nn] + (double)b[nn]) + 1e-4;
    double wsum = 0.0, hsum = 0.0;
#pragma unroll
    for (int i = 0; i < NK1; ++i) { wsum += pr[i]; hsum += pr[NK1 + i]; }
    const double iws = 1.0 / wsum, ihs = 1.0 / hsum;
    double cumx[NK1+1], cumy[NK1+1], dfull[NK1+1];
    cumx[0]=0.0; cumy[0]=0.0; dfull[0]=1.0;
#pragma unroll
    for (int i = 0; i < NK1; ++i) {
        cumx[i+1] = cumx[i] + pr[i]*iws;
        cumy[i+1] = cumy[i] + pr[NK1+i]*ihs;
        dfull[i+1] = pr[2*NK1+i];
    }
    const int e0 = half * 64, eend = e0 + 64;
    int e = e0; double prevF = 0.0;
    float* orow = out + (row0 + rl) * 128;
#define BIN_BODY(bin_) { \
    const double cx=cumx[bin_], cxn=((bin_)<8)?cumx[(bin_)+1]:1.0e300, cy=cumy[bin_]; \
    const double wb=cumx[(bin_)+1]-cx, hb=cumy[(bin_)+1]-cy; \
    const double iw=1.0/wb, dl=hb*iw, db=dfull[bin_], db1=dfull[(bin_)+1]; \
    const double sc=db+db1-2.0*dl; \
    while (e <= eend) { \
        const double x=(double)e*0.0078125; \
        if (x > cxn) break; \
        const double th=(x-cx)*iw, t1m=th*(1.0-th); \
        const double num=hb*(dl*th*th+db*t1m), den=dl+sc*t1m; \
        const double F=cy+num/den; \
        if (e > e0) orow[e-1] = logf(fmaxf((float)(F-prevF), 1e-8f)); \
        prevF=F; ++e; \
    } }
    BIN_BODY(0) BIN_BODY(1) BIN_BODY(2) BIN_BODY(3) BIN_BODY(4)
    BIN_BODY(5) BIN_BODY(6) BIN_BODY(7) BIN_BODY(8)
#undef BIN_BODY
}

// ---------------------------------------------------------------------------
extern "C" void kernel_launch(void* const* d_in, const int* in_sizes, int n_in,
                              void* d_out, int out_size, void* d_ws, size_t ws_size,
                              hipStream_t stream) {
    const float* h = (const float*)d_in[0];
    const float* W = (const float*)d_in[1];
    const float* b = (const float*)d_in[2];
    float* out = (float*)d_out;

    const int rows = in_sizes[0] / IN_DIM;   // 131072
    const size_t need = (size_t)OUT_DIM * rows * sizeof(float);   // 14.2 MB

    if (ws_size >= need) {
        float* paramsT = (float*)d_ws;
        gemv_params3 <<<rows / 64, 256, 0, stream>>>(h, W, b, paramsT, rows);
        spline_eval3 <<<rows / 4,  256, 0, stream>>>(paramsT, out, rows);
    } else {
        rqs_head_fallback<<<rows / 128, 256, 0, stream>>>(h, W, b, out);
    }
}